// Round 9
// baseline (1050.916 us; speedup 1.0000x reference)
//
#include <hip/hip_runtime.h>
#include <hip/hip_bf16.h>
#include <math.h>

// TitanLongTermMemory — round 15: full m201 geometry (256x256, per-wave 128x64).
// r14 post-mortem: pgemm 92.5us but MfmaUtil 23% — per-wave 64x64 gives 0.5
// ds_read/MFMA; per-phase LDS time >= MFMA time, lockstep phases serialize.
// qgemm: BM=BN=256, BK=64, 8 waves 2Mx4N, acc[8][4] (0.375 reads/MFMA),
// 2buf x 2half LDS (128KB), 4 phases/K-tile, half-tile staging with counted
// vmcnt(8)/vmcnt(4) per m201's formula; sched_barrier(0) after lgkm (rule 18).
// N=3200 -> padded 3328 (13 x 256) with zeroed W4/bias4 pad rows.
// Expected: 828 -> ~700us; x-proj 92.5 -> ~50us, MfmaUtil -> 45-60%.

using bf16 = __hip_bfloat16;

typedef __attribute__((ext_vector_type(8))) short bf16x8;
typedef __attribute__((ext_vector_type(4))) float f32x4;

__device__ __forceinline__ float ldf(const bf16* p) { return __bfloat162float(*p); }
__device__ __forceinline__ float ldf(const float* p) { return *p; }
__device__ __forceinline__ void stf(bf16* p, float v) { *p = __float2bfloat16(v); }
__device__ __forceinline__ void stf(float* p, float v) { *p = v; }
__device__ __forceinline__ float b2f(const bf16& b) { return __bfloat162float(b); }
__device__ __forceinline__ float bsf(short s) {
  union { unsigned u; float f; } cv;
  cv.u = (unsigned)(unsigned short)s << 16;
  return cv.f;
}

enum { ACT_NONE = 0, ACT_SILU = 1, ACT_SIGMOID = 2, ACT_GATE = 3, ACT_PSILU = 4 };

__global__ void detect_kernel(const unsigned short* g, int* flag) {
  if (threadIdx.x == 0) *flag = (g[0] != 0) ? 1 : 0;
}

// ---- single fused dtype-normalize for all non-x inputs ----------------------
struct ConvArgs {
  const void* src[29];
  bf16* dst[29];
  int n[29];
  int bstart[30];
};

__global__ __launch_bounds__(256) void convall_kernel(ConvArgs a, const int* __restrict__ flag) {
  int b = blockIdx.x;
  int ti = 0;
  while (ti < 28 && b >= a.bstart[ti + 1]) ++ti;
  int i = (b - a.bstart[ti]) * 256 + threadIdx.x;
  if (i >= a.n[ti]) return;
  if (*flag) a.dst[ti][i] = ((const bf16*)a.src[ti])[i];
  else a.dst[ti][i] = __float2bfloat16(((const float*)a.src[ti])[i]);
}

// vectorized x-chunk convert: 8 elems/thread
__global__ __launch_bounds__(256) void conv_kernel(
    const void* __restrict__ src, bf16* __restrict__ dst, int n, size_t src_off,
    const int* __restrict__ flag) {
  int i = (blockIdx.x * 256 + threadIdx.x) * 8;
  if (i >= n) return;
  if (*flag) {
    *(uint4*)((unsigned short*)dst + i) =
        *(const uint4*)((const unsigned short*)src + src_off + i);
  } else {
    const float* s = (const float*)src + src_off + i;
    const float4 a = *(const float4*)s;
    const float4 b = *(const float4*)(s + 4);
    bf16 t[8] = {__float2bfloat16(a.x), __float2bfloat16(a.y),
                 __float2bfloat16(a.z), __float2bfloat16(a.w),
                 __float2bfloat16(b.x), __float2bfloat16(b.y),
                 __float2bfloat16(b.z), __float2bfloat16(b.w)};
    *(uint4*)((unsigned short*)dst + i) = *(const uint4*)t;
  }
}

__global__ __launch_bounds__(256) void zerobf_kernel(bf16* __restrict__ p, int n) {
  int i = blockIdx.x * 256 + threadIdx.x;
  if (i < n) p[i] = __float2bfloat16(0.f);
}

// bias4 = [bk(1024) | bv(1024) | bq(1024) | mem_b1(128) | pad0(128)]
__global__ __launch_bounds__(256) void pack_bias4(
    const bf16* __restrict__ bk, const bf16* __restrict__ bv,
    const bf16* __restrict__ bq, const bf16* __restrict__ b1,
    bf16* __restrict__ o) {
  int j = blockIdx.x * 256 + threadIdx.x;
  if (j >= 3328) return;
  float v = 0.f;
  if (j < 1024) v = b2f(bk[j]);
  else if (j < 2048) v = b2f(bv[j - 1024]);
  else if (j < 3072) v = b2f(bq[j - 2048]);
  else if (j < 3200) v = b2f(b1[j - 3072]);
  o[j] = __float2bfloat16(v);
}

// 64x64-tile transpose: dst[c][r] = src[r][c]; src rows x cols (ld=cols).
__global__ __launch_bounds__(256) void transpose_kernel(
    const bf16* __restrict__ srcb, bf16* __restrict__ dstb, int rows, int cols) {
  __shared__ unsigned short t[64][72];  // 144B row stride (16B-aligned)
  const unsigned short* src = (const unsigned short*)srcb;
  unsigned short* dst = (unsigned short*)dstb;
  const int r0 = blockIdx.y * 64, c0 = blockIdx.x * 64;
  for (int e = threadIdx.x; e < 64 * 8; e += 256) {
    int r = e >> 3, c8 = e & 7;
    uint4 v = *(const uint4*)(src + (size_t)(r0 + r) * cols + c0 + c8 * 8);
    *(uint4*)&t[r][c8 * 8] = v;
  }
  __syncthreads();
  for (int e = threadIdx.x; e < 64 * 8; e += 256) {
    int c = e >> 3, r8 = (e & 7) * 8;
    unsigned short v[8];
#pragma unroll
    for (int j = 0; j < 8; ++j) v[j] = t[r8 + j][c];
    *(uint4*)(dst + (size_t)(c0 + c) * rows + r0 + r8) = *(uint4*)v;
  }
}

// ---- fused kp/vp/bkv GEMV over W4 rows 0..2047 ([Wkk|Wvv]) ------------------
__global__ __launch_bounds__(256) void kpvp_kernel(
    const bf16* __restrict__ pmb, const bf16* __restrict__ mobb,
    const bf16* __restrict__ Wb, const bf16* __restrict__ bias4b,
    bf16* __restrict__ kp, bf16* __restrict__ vp, bf16* __restrict__ bkv)
{
  const short* pm = (const short*)pmb;
  const short* mob = (const short*)mobb;
  const short* W = (const short*)Wb;
  const int wave = threadIdx.x >> 6, lane = threadIdx.x & 63;
  const int c = blockIdx.x * 4 + wave;  // 0..2047
  const short* wrow = W + (size_t)c * 1024 + lane * 16;
  const bf16x8 w0 = *(const bf16x8*)wrow;
  const bf16x8 w1 = *(const bf16x8*)(wrow + 8);
  float acc[5];
#pragma unroll
  for (int m = 0; m < 5; ++m) {
    const short* prow = (m < 4) ? (pm + m * 1024 + lane * 16) : (mob + lane * 16);
    const bf16x8 p0 = *(const bf16x8*)prow;
    const bf16x8 p1 = *(const bf16x8*)(prow + 8);
    float s = 0.f;
#pragma unroll
    for (int j = 0; j < 8; ++j) s += bsf(w0[j]) * bsf(p0[j]) + bsf(w1[j]) * bsf(p1[j]);
    acc[m] = s;
  }
#pragma unroll
  for (int d = 1; d < 64; d <<= 1) {
#pragma unroll
    for (int m = 0; m < 5; ++m) acc[m] += __shfl_xor(acc[m], d);
  }
  if (lane == 0) {
    const float bv = b2f(bias4b[c]);
    bf16* dst = (c < 1024) ? (kp + c) : (vp + (c - 1024));
#pragma unroll
    for (int m = 0; m < 4; ++m) stf(dst + m * 1024, acc[m] + bv);
    stf(&bkv[c], acc[4] + bv);
  }
}

__device__ __forceinline__ void gl_lds16(const short* g, short* l) {
  __builtin_amdgcn_global_load_lds(
      (const __attribute__((address_space(1))) void*)g,
      (__attribute__((address_space(3))) void*)l, 16, 0, 0);
}

// ---------------- r12 MFMA GEMM (verified) — small/fallback shapes ----------
template <typename TC, int ACT, bool HAS_BIAS>
__global__ __launch_bounds__(256) void mgemm(
    const bf16* __restrict__ Ab, const bf16* __restrict__ Bw,
    const bf16* __restrict__ bias, TC* __restrict__ C,
    int M, int N, int K, int lda, int ldc,
    const bf16* __restrict__ ao, const void* __restrict__ xsrc, size_t xoff,
    const int* __restrict__ flag, int pn)
{
  __shared__ short As[2][128 * 32];
  __shared__ short Bs[2][128 * 32];
  const short* A = (const short*)Ab;
  const short* B = (const short*)Bw;
  const int tid = threadIdx.x;
  const int m0 = blockIdx.x * 128, n0 = blockIdx.y * 128;
  const int wave = tid >> 6, lane = tid & 63;
  const int wm = (wave & 1) * 64, wn = (wave >> 1) * 64;
  const int fm = lane & 15;
  const int fq = lane >> 4;
  const int fks = (fq ^ ((fm >> 1) & 3)) * 8;   // swizzled read col (shorts)

  const int srow = tid >> 2;
  const int scol = ((tid & 3) ^ ((tid >> 3) & 3)) * 8;  // swizzled source col
  const short* gA0 = A + (size_t)(m0 + srow) * lda + scol;
  const short* gA1 = A + (size_t)(m0 + 64 + srow) * lda + scol;
  const short* gB0 = B + (size_t)(n0 + srow) * K + scol;
  const short* gB1 = B + (size_t)(n0 + 64 + srow) * K + scol;

  f32x4 acc[4][4] = {};
  const int NT = K >> 5;

#define STAGE(buf, k0)                              \
  do {                                              \
    gl_lds16(gA0 + (k0), &As[buf][tid * 8]);        \
    gl_lds16(gA1 + (k0), &As[buf][(256 + tid) * 8]);\
    gl_lds16(gB0 + (k0), &Bs[buf][tid * 8]);        \
    gl_lds16(gB1 + (k0), &Bs[buf][(256 + tid) * 8]);\
  } while (0)

  STAGE(0, 0);
  STAGE(1, 32);

  for (int kt = 0; kt < NT; ++kt) {
    const int cur = kt & 1;
    if (kt == NT - 1) asm volatile("s_waitcnt vmcnt(0)" ::: "memory");
    else              asm volatile("s_waitcnt vmcnt(4)" ::: "memory");
    __builtin_amdgcn_s_barrier();
    bf16x8 af[4], bfr[4];
#pragma unroll
    for (int i = 0; i < 4; ++i)
      af[i] = *(const bf16x8*)&As[cur][(wm + i * 16 + fm) * 32 + fks];
#pragma unroll
    for (int j = 0; j < 4; ++j)
      bfr[j] = *(const bf16x8*)&Bs[cur][(wn + j * 16 + fm) * 32 + fks];
#pragma unroll
    for (int i = 0; i < 4; ++i)
#pragma unroll
      for (int j = 0; j < 4; ++j)
        acc[i][j] = __builtin_amdgcn_mfma_f32_16x16x32_bf16(af[i], bfr[j], acc[i][j], 0, 0, 0);
    asm volatile("s_waitcnt lgkmcnt(0)" ::: "memory");
    __builtin_amdgcn_s_barrier();
    if (kt + 2 < NT) STAGE(cur, (kt + 2) * 32);
  }
#undef STAGE

  const int rg = fq * 4;
#pragma unroll
  for (int i = 0; i < 4; ++i) {
#pragma unroll
    for (int j = 0; j < 4; ++j) {
      const int n = n0 + wn + j * 16 + fm;
      float bv = 0.f;
      if (HAS_BIAS) bv = b2f(bias[n]);
#pragma unroll
      for (int r = 0; r < 4; ++r) {
        const int m = m0 + wm + i * 16 + rg + r;
        float v = acc[i][j][r] + bv;
        if (ACT == ACT_SILU) v = v / (1.f + __expf(-v));
        if (ACT == ACT_PSILU) { if (n >= pn) v = v / (1.f + __expf(-v)); }
        if (ACT == ACT_SIGMOID) v = 1.f / (1.f + __expf(-v));
        if (ACT == ACT_GATE) {
          v = 1.f / (1.f + __expf(-v));
          const size_t e = (size_t)m * 1024 + n;
          const float xv = *flag ? b2f(((const bf16*)xsrc)[xoff + e])
                                 : ((const float*)xsrc)[xoff + e];
          v = v * b2f(ao[e]) + xv;
        }
        stf(&C[(size_t)m * ldc + n], v);
      }
    }
  }
}

// ---------------- qgemm: m201 geometry — 256x256, BK=64, per-wave 128x64 ----
// 8 waves (2Mx4N), acc[8][4]. LDS 2buf x 2half x {A 256x32, B 256x32} = 128KB.
// 4 phases/K-tile: (h,njp). Phase: {ds_read (af[8] if njp==0, bf[2]) ∥ issue
// one half-tile stage (4 gl_lds) -> barrier -> lgkm(0)+sched_barrier ->
// setprio(1) 16 MFMA setprio(0) -> [vmcnt(8) end-ph1 / vmcnt(4) end-ph3]
// -> barrier}. vmcnt(0) only in the last tile. Requires M%256==0, N%256==0,
// K%64==0, K>=128.
template <typename TC, int ACT, bool HAS_BIAS>
__global__ __launch_bounds__(512, 1) void qgemm(
    const bf16* __restrict__ Ab, const bf16* __restrict__ Bw,
    const bf16* __restrict__ bias, TC* __restrict__ C,
    int M, int N, int K, int lda, int ldc,
    const bf16* __restrict__ ao, const void* __restrict__ xsrc, size_t xoff,
    const int* __restrict__ flag, int pn)
{
  __shared__ short LA[2][2][256 * 32];   // [buf][half][row*32]
  __shared__ short LB[2][2][256 * 32];
  const short* A = (const short*)Ab;
  const short* B = (const short*)Bw;
  const int tid = threadIdx.x;
  const int m0 = blockIdx.x * 256, n0 = blockIdx.y * 256;
  const int wave = tid >> 6, lane = tid & 63;
  const int wm = (wave & 1) * 128;     // 2 m-halves
  const int wn = (wave >> 1) * 64;     // 4 n-quarters
  const int fm = lane & 15;
  const int fq = lane >> 4;
  const int grp = (fq ^ ((fm >> 1) & 3)) * 8;   // swizzled read group

  const int srow = tid >> 2;                              // 0..127
  const int sg = ((tid & 3) ^ ((tid >> 3) & 3)) * 8;      // inverse-swz src col
  const short* aS0 = A + (size_t)(m0 + srow) * lda + sg;
  const short* aS1 = A + (size_t)(m0 + 128 + srow) * lda + sg;
  const short* bS0 = B + (size_t)(n0 + srow) * K + sg;
  const short* bS1 = B + (size_t)(n0 + 128 + srow) * K + sg;

  f32x4 acc[8][4] = {};
  const int NT = K >> 6;

#define QSTG(b, t, h)                                     \
  do {                                                    \
    const int ks_ = (t) * 64 + (h) * 32;                  \
    gl_lds16(aS0 + ks_, &LA[b][h][tid * 8]);              \
    gl_lds16(aS1 + ks_, &LA[b][h][4096 + tid * 8]);       \
    gl_lds16(bS0 + ks_, &LB[b][h][tid * 8]);              \
    gl_lds16(bS1 + ks_, &LB[b][h][4096 + tid * 8]);       \
  } while (0)

  QSTG(0, 0, 0);
  QSTG(0, 0, 1);
  asm volatile("s_waitcnt vmcnt(4)" ::: "memory");   // half0 of tile 0 landed
  __builtin_amdgcn_s_barrier();

  bf16x8 af[8], bf[2];

  for (int t = 0; t < NT; ++t) {
    const int c = t & 1, s = c ^ 1;
    const bool nx = (t + 1) < NT;
#pragma unroll
    for (int h = 0; h < 2; ++h) {
#pragma unroll
      for (int njp = 0; njp < 2; ++njp) {
        const short* la = &LA[c][h][0];
        const short* lb = &LB[c][h][0];
        if (njp == 0) {
#pragma unroll
          for (int mi = 0; mi < 8; ++mi)
            af[mi] = *(const bf16x8*)&la[(wm + mi * 16 + fm) * 32 + grp];
        }
#pragma unroll
        for (int j = 0; j < 2; ++j)
          bf[j] = *(const bf16x8*)&lb[(wn + (njp * 2 + j) * 16 + fm) * 32 + grp];
        if (h == 0 && nx) QSTG(s, t + 1, njp);  // ph0: next.h0, ph1: next.h1
        __builtin_amdgcn_s_barrier();
        asm volatile("s_waitcnt lgkmcnt(0)" ::: "memory");
        __builtin_amdgcn_sched_barrier(0);
        __builtin_amdgcn_s_setprio(1);
#pragma unroll
        for (int mi = 0; mi < 8; ++mi)
#pragma unroll
          for (int j = 0; j < 2; ++j)
            acc[mi][njp * 2 + j] = __builtin_amdgcn_mfma_f32_16x16x32_bf16(
                af[mi], bf[j], acc[mi][njp * 2 + j], 0, 0, 0);
        __builtin_amdgcn_s_setprio(0);
        if (h == 0 && njp == 1) {              // end of phase 1
          if (nx) asm volatile("s_waitcnt vmcnt(8)" ::: "memory");
          else    asm volatile("s_waitcnt vmcnt(0)" ::: "memory");
        }
        if (h == 1 && njp == 1 && nx)          // end of phase 3
          asm volatile("s_waitcnt vmcnt(4)" ::: "memory");
        __builtin_amdgcn_s_barrier();
      }
    }
  }
#undef QSTG

#pragma unroll
  for (int mi = 0; mi < 8; ++mi) {
#pragma unroll
    for (int nj = 0; nj < 4; ++nj) {
      const int n = n0 + wn + nj * 16 + fm;
      float bv = 0.f;
      if (HAS_BIAS) bv = b2f(bias[n]);
#pragma unroll
      for (int r = 0; r < 4; ++r) {
        const int m = m0 + wm + mi * 16 + fq * 4 + r;
        float v = acc[mi][nj][r] + bv;
        if (ACT == ACT_SILU) v = v / (1.f + __expf(-v));
        if (ACT == ACT_PSILU) { if (n >= pn) v = v / (1.f + __expf(-v)); }
        if (ACT == ACT_SIGMOID) v = 1.f / (1.f + __expf(-v));
        if (ACT == ACT_GATE) {
          v = 1.f / (1.f + __expf(-v));
          const size_t e = (size_t)m * 1024 + n;
          const float xv = *flag ? b2f(((const bf16*)xsrc)[xoff + e])
                                 : ((const float*)xsrc)[xoff + e];
          v = v * b2f(ao[e]) + xv;
        }
        stf(&C[(size_t)m * ldc + n], v);
      }
    }
  }
}

// ---- K-split fold GEMM (preamble): P[z] = A @ B^T over K-slice z (KS=4) ----
__global__ __launch_bounds__(256) void kgemm(
    const bf16* __restrict__ Ab, const bf16* __restrict__ Bw,
    float* __restrict__ P, int M, int N, int K, int lda)
{
  __shared__ short As[128 * 32];
  __shared__ short Bs[128 * 32];
  const short* A = (const short*)Ab;
  const short* B = (const short*)Bw;
  const int tid = threadIdx.x;
  const int m0 = blockIdx.x * 128, n0 = blockIdx.y * 128;
  const int kb = blockIdx.z * (K >> 2), ke = kb + (K >> 2);
  const int wave = tid >> 6, lane = tid & 63;
  const int wm = (wave & 1) * 64, wn = (wave >> 1) * 64;
  const int fm = lane & 15;
  const int fk = (lane >> 4) * 8;

  const int srow = tid >> 2, scol = (tid & 3) * 8;
  const short* gA0 = A + (size_t)(m0 + srow) * lda + scol;
  const short* gA1 = A + (size_t)(m0 + 64 + srow) * lda + scol;
  const short* gB0 = B + (size_t)(n0 + srow) * K + scol;
  const short* gB1 = B + (size_t)(n0 + 64 + srow) * K + scol;
  short* lA0 = As + tid * 8;
  short* lA1 = As + (256 + tid) * 8;
  short* lB0 = Bs + tid * 8;
  short* lB1 = Bs + (256 + tid) * 8;

  f32x4 acc[4][4] = {};

  for (int k0 = kb; k0 < ke; k0 += 32) {
    gl_lds16(gA0 + k0, lA0);
    gl_lds16(gA1 + k0, lA1);
    gl_lds16(gB0 + k0, lB0);
    gl_lds16(gB1 + k0, lB1);
    __syncthreads();
    bf16x8 af[4], bfr[4];
#pragma unroll
    for (int i = 0; i < 4; ++i)
      af[i] = *(const bf16x8*)&As[(wm + i * 16 + fm) * 32 + fk];
#pragma unroll
    for (int j = 0; j < 4; ++j)
      bfr[j] = *(const bf16x8*)&Bs[(wn + j * 16 + fm) * 32 + fk];
#pragma unroll
    for (int i = 0; i < 4; ++i)
#pragma unroll
      for (int j = 0; j < 4; ++j)
        acc[i][j] = __builtin_amdgcn_mfma_f32_16x16x32_bf16(af[i], bfr[j], acc[i][j], 0, 0, 0);
    __syncthreads();
  }

  float* Cp = P + (size_t)blockIdx.z * ((size_t)M * N);
  const int rg = (lane >> 4) * 4;
#pragma unroll
  for (int i = 0; i < 4; ++i)
#pragma unroll
    for (int j = 0; j < 4; ++j) {
      const int n = n0 + wn + j * 16 + fm;
#pragma unroll
      for (int r = 0; r < 4; ++r) {
        const int m = m0 + wm + i * 16 + rg + r;
        Cp[(size_t)m * N + n] = acc[i][j][r];
      }
    }
}

// sum 4 K-slice partials -> bf16
__global__ __launch_bounds__(256) void foldfin_kernel(
    const float* __restrict__ P, bf16* __restrict__ o, int MN) {
  int i = blockIdx.x * 256 + threadIdx.x;
  if (i >= MN) return;
  float s = P[i] + P[i + (size_t)MN] + P[i + 2 * (size_t)MN] + P[i + 3 * (size_t)MN];
  o[i] = __float2bfloat16(s);
}

// Row LayerNorm over width W; optional post-LN add of a bf16 vector.
template <typename TI, typename TO, bool ADD, int W, int BS>
__global__ __launch_bounds__(BS) void ln_kernel(
    const TI* __restrict__ in, const bf16* __restrict__ g, const bf16* __restrict__ b,
    const bf16* __restrict__ addv, TO* __restrict__ out, int ldin)
{
  __shared__ float red[BS];
  const int row = blockIdx.x;
  const TI* rin = in + (size_t)row * ldin;
  TO* rout = out + (size_t)row * W;
  const int NP = W / BS;
  float v[NP];
  float s = 0.f;
#pragma unroll
  for (int i = 0; i < NP; ++i) { v[i] = ldf(&rin[threadIdx.x + i * BS]); s += v[i]; }
  red[threadIdx.x] = s; __syncthreads();
  for (int o = BS / 2; o > 0; o >>= 1) {
    if (threadIdx.x < o) red[threadIdx.x] += red[threadIdx.x + o];
    __syncthreads();
  }
  const float mean = red[0] / W;
  __syncthreads();
  float sq = 0.f;
#pragma unroll
  for (int i = 0; i < NP; ++i) { float d = v[i] - mean; sq += d * d; }
  red[threadIdx.x] = sq; __syncthreads();
  for (int o = BS / 2; o > 0; o >>= 1) {
    if (threadIdx.x < o) red[threadIdx.x] += red[threadIdx.x + o];
    __syncthreads();
  }
  const float rstd = rsqrtf(red[0] / W + 1e-5f);
#pragma unroll
  for (int i = 0; i < NP; ++i) {
    int c = threadIdx.x + i * BS;
    float o_ = (v[i] - mean) * rstd * b2f(g[c]) + b2f(b[c]);
    if (ADD) o_ += b2f(addv[c]);
    stf(&rout[c], o_);
  }
}

// ---------------- MFMA attention (XCD-chunked bid swizzle) ------------------
__global__ __launch_bounds__(512) void attn_kernel(
    const bf16* __restrict__ qg, int str_q,
    const bf16* __restrict__ krv, int str_r,
    const bf16* __restrict__ kxv, int str_x, const bf16* __restrict__ kpg,
    const bf16* __restrict__ vpg, bf16* __restrict__ outg)
{
  __shared__ short qs[4 * 64 * 32];
  __shared__ short ksl[4 * 144 * 32];
  __shared__ short vt[128 * 168];
  __shared__ short pl[64 * 168];

  const int tid = threadIdx.x;
  unsigned bid = blockIdx.x;
  {
    const unsigned nwg = gridDim.x;
    const unsigned q_ = nwg >> 3, r_ = nwg & 7;
    const unsigned xcd = bid & 7, loc = bid >> 3;
    bid = (xcd < r_ ? xcd * (q_ + 1) : r_ * (q_ + 1) + (xcd - r_) * q_) + loc;
  }
  const int seg = (int)(bid >> 3), h = (int)(bid & 7);
  const unsigned short* q = (const unsigned short*)qg + (size_t)seg * 64 * str_q + h * 128;
  const unsigned short* kv_r = (const unsigned short*)krv + (size_t)seg * 64 * str_r + h * 128;
  const unsigned short* kv_x = (const unsigned short*)kxv + (size_t)seg * 64 * str_x + h * 128;
  const unsigned short* kp = (const unsigned short*)kpg;
  const unsigned short* vp = (const unsigned short*)vpg;
  const size_t obase = (size_t)seg * 64 * 1024 + h * 128;

  for (int ch = tid; ch < 64 * 16; ch += 512) {
    int row = ch >> 4, k8 = ch & 15;
    uint4 v = *(const uint4*)(q + (size_t)row * str_q + k8 * 8);
    *(uint4*)&qs[((k8 >> 2) * 64 + row) * 32 + (k8 & 3) * 8] = v;
  }
  for (int ch = tid; ch < 132 * 16; ch += 512) {
    int t = ch >> 4, k8 = ch & 15;
    const unsigned short* src;
    if (t < 64) src = kv_r + (size_t)t * str_r;
    else if (t < 68) src = kp + (size_t)(t - 64) * 1024 + h * 128;
    else src = kv_x + (size_t)(t - 68) * str_x;
    uint4 v = *(const uint4*)(src + k8 * 8);
    *(uint4*)&ksl[((k8 >> 2) * 144 + t) * 32 + (k8 & 3) * 8] = v;
  }
  __syncthreads();

  const int wave = tid >> 6, lane = tid & 63;
  const int fm = lane & 15, fq = lane >> 4;

  if (wave < 4) {
    const int s0 = wave * 16;
    f32x4 acc[10];
#pragma unroll
    for (int tt = 0; tt < 10; ++tt) acc[tt] = (f32x4){0.f, 0.f, 0.f, 0.f};
#pragma unroll
    for (int kb = 0; kb < 4; ++kb) {
      const bf16x8 a = *(const bf16x8*)&qs[(kb * 64 + s0 + fm) * 32 + fq * 8];
#pragma unroll
      for (int tt = 0; tt < 9; ++tt) {
        const bf16x8 b = *(const bf16x8*)&ksl[(kb * 144 + tt * 16 + fm) * 32 + fq * 8];
        acc[tt] = __builtin_amdgcn_mfma_f32_16x16x32_bf16(a, b, acc[tt], 0, 0, 0);
      }
    }
    const float scale = 0.08838834764831845f;
#pragma unroll
    for (int r = 0; r < 4; ++r) {
      float m = -3.0e38f;
#pragma unroll
      for (int tt = 0; tt < 9; ++tt) {
        int t = tt * 16 + fm;
        if (t < 132) m = fmaxf(m, acc[tt][r] * scale);
      }
      for (int d = 1; d < 16; d <<= 1) m = fmaxf(m, __shfl_xor(m, d));
      float e[10];
      float sum = 0.f;
#pragma unroll
      for (int tt = 0; tt < 10; ++tt) {
        int t = tt * 16 + fm;
        float ev = 0.f;
        if (t < 132) ev = __expf(acc[tt][r] * scale - m);
        e[tt] = ev; sum += ev;
      }
      for (int d = 1; d < 16; d <<= 1) sum += __shfl_xor(sum, d);
      const float inv = 1.f / sum;
      const int s = s0 + fq * 4 + r;
#pragma unroll
      for (int tt = 0; tt < 10; ++tt) {
        bf16 pv = __float2bfloat16(e[tt] * inv);
        pl[s * 168 + tt * 16 + fm] = *(const short*)&pv;
      }
    }
  } else {
    for (int ch = tid - 256; ch < 132 * 32; ch += 256) {
      int t = ch >> 5, d4 = (ch & 31) * 4;
      const unsigned short* src;
      if (t < 64) src = kv_r + 1024 + (size_t)t * str_r;
      else if (t < 68) src = vp + (size_t)(t - 64) * 1024 + h * 128;
      else src = kv_x + 1024 + (size_t)(t - 68) * str_x;
      uint2 w = *(const uint2*)(src + d4);
      vt[(d4 + 0) * 168 + t] = (short)(w.x & 0xffffu);
      vt[(d4 + 1) * 168 + t] = (short)(w.x >> 16);
      vt[(d4 + 2) * 168 + t] = (short)(w.y & 0xffffu);
      vt[(d4 + 3) * 168 + t] = (short)(w.y >> 16);
    }
    for (int ch = tid - 256; ch < 128 * 32; ch += 256) {
      int d = ch >> 5, tp = 132 + (ch & 31);
      vt[d * 168 + tp] = 0;
    }
  }
  __syncthreads();

  const int dt = wave;
  bf16x8 af[5];
#pragma unroll
  for (int kb = 0; kb < 5; ++kb)
    af[kb] = *(const bf16x8*)&vt[(dt * 16 + fm) * 168 + kb * 32 + fq * 8];
#pragma unroll
  for (int st = 0; st < 4; ++st) {
    f32x4 o = (f32x4){0.f, 0.f, 0.f, 0.f};
#pragma unroll
    for (int kb = 0; kb < 5; ++kb) {
      const bf16x8 bp = *(const bf16x8*)&pl[(st * 16 + fm) * 168 + kb * 32 + fq * 8];
      o = __builtin_amdgcn_mfma_f32_16x16x32_bf16(af[kb], bp, o, 0, 0, 0);
    }
    const int s = st * 16 + fm;
    bf16 b0 = __float2bfloat16(o[0]), b1 = __float2bfloat16(o[1]);
    bf16 b2 = __float2bfloat16(o[2]), b3 = __float2bfloat16(o[3]);
    uint2 w;
    w.x = ((unsigned)(*(unsigned short*)&b1) << 16) | (*(unsigned short*)&b0);
    w.y = ((unsigned)(*(unsigned short*)&b3) << 16) | (*(unsigned short*)&b2);
    *(uint2*)((unsigned short*)outg + obase + (size_t)s * 1024 + dt * 16 + fq * 4) = w;
  }
}

extern "C" void kernel_launch(void* const* d_in, const int* in_sizes, int n_in,
                              void* d_out, int out_size, void* d_ws, size_t ws_size,
                              hipStream_t stream)
{
  (void)n_in; (void)out_size;
  const int R = 16384, Cd = 1024;
  const int NP4 = 3328;   // padded packed-projection width (13 x 256)

  char* ws = (char*)d_ws;
  size_t off = 0;
  auto alloc = [&](size_t bytes) -> void* {
    void* p = ws + off;
    off += (bytes + 255) & ~(size_t)255;
    return p;
  };

  int* flag = (int*)alloc(256);
  // packed x-projection weights [Wkk | Wvv | Wqq | Wm1 | pad0] (3328 x 1024)
  bf16* W4    = (bf16*)alloc((size_t)NP4 * Cd * sizeof(bf16));
  bf16* bias4 = (bf16*)alloc(NP4 * sizeof(bf16));
  bf16* T     = (bf16*)alloc((size_t)Cd * Cd * sizeof(bf16));  // transpose scratch
  bf16* Wc    = (bf16*)alloc((size_t)2048 * 128 * sizeof(bf16));
  bf16* kp    = (bf16*)alloc((size_t)4 * Cd * sizeof(bf16));
  bf16* vp    = (bf16*)alloc((size_t)4 * Cd * sizeof(bf16));
  bf16* bkv   = (bf16*)alloc(2048 * sizeof(bf16));
  bf16* WqStk = (bf16*)alloc((size_t)1152 * Cd * sizeof(bf16)); // [mhaWq; mem_W1]
  bf16* nb[30];
  nb[0] = nullptr;
  for (int i = 1; i < 30; ++i) nb[i] = (bf16*)alloc((size_t)in_sizes[i] * sizeof(bf16));
  nb[16] = WqStk;                          // mhaWq -> rows 0..1023 of stack
  nb[5]  = WqStk + (size_t)1024 * Cd;      // mem_W1 -> rows 1024..1151
  const size_t fixed_end = off;

  // balanced chunk sizing; per-row scratch = 17408 B
  size_t avail = (ws_size > fixed_end + (1u << 20)) ? (ws_size - fixed_end - (1u << 20)) : 0;
  int crmax = (int)(avail / 17408);
  if (crmax > R) crmax = R;
  if (crmax < 256) crmax = 256;
  int nch = (R + crmax - 1) / crmax;
  int CR = ((R / nch + 255) / 256) * 256;
  while (CR * nch < R) CR += 256;

  const size_t chunk_start = off;
  const size_t RB = (size_t)CR * Cd * sizeof(bf16);
  bf16* Xc  = (bf16*)alloc(RB);                               // x(bf16) -> attn out
  bf16* QS4 = (bf16*)alloc((size_t)CR * NP4 * sizeof(bf16));  // [k_x|v_x|q|h1|pad]
  bf16* h1b = (bf16*)alloc((size_t)CR * 128 * sizeof(bf16));
  bf16* h2b = (bf16*)alloc((size_t)CR * 128 * sizeof(bf16));
  bf16* Bb  = (bf16*)alloc(RB);                               // ao
  bf16* KVr = (bf16*)alloc(2 * RB);                           // [k_r | v_r]
  bf16* Cc  = (bf16*)alloc(RB);                               // gin
  const size_t chunk_bytes = off - chunk_start;

  dim3 blk(256);
  // grid = (Mt, Nt): m-tile fastest -> xcd = m_tile % 8 fixed
  auto g128 = [](int M_, int N_) { return dim3((unsigned)(M_ / 128), (unsigned)(N_ / 128)); };
  auto g256 = [](int M_, int N_) { return dim3((unsigned)(M_ / 256), (unsigned)(N_ / 256)); };

  // ---- preamble ----
  detect_kernel<<<1, 64, 0, stream>>>((const unsigned short*)d_in[24], flag);
  {
    ConvArgs a;
    int bs = 0;
    for (int i = 1; i < 30; ++i) {
      a.src[i - 1] = d_in[i];
      a.dst[i - 1] = nb[i];
      a.n[i - 1] = in_sizes[i];
      a.bstart[i - 1] = bs;
      bs += (in_sizes[i] + 255) / 256;
    }
    a.bstart[29] = bs;
    convall_kernel<<<dim3((unsigned)bs), blk, 0, stream>>>(a, flag);
  }
  const bf16 *pm = nb[1], *Wq = nb[2], *Wk = nb[3], *Wv = nb[4];
  const bf16 *mem_W1 = nb[5], *mem_b1 = nb[6], *ln1g = nb[7], *ln1b = nb[8];
  const bf16 *mem_W2 = nb[9], *mem_b2 = nb[10], *ln2g = nb[11], *ln2b = nb[12];
  const bf16 *mem_oW = nb[13], *mem_ob = nb[14], *mstate = nb[15];
  const bf16 *mhaWq = nb[16], *mhabq = nb[17], *mhaWk = nb[18], *mhabk = nb[19];
  const bf16 *mhaWv = nb[20], *mhabv = nb[21], *mhaWo = nb[22], *mhabo = nb[23];
  const bf16 *gn_g = nb[24], *gn_b = nb[25], *gateW = nb[26], *gateb = nb[27];
  const bf16 *outW = nb[28], *outb = nb[29];
  bf16* Wkk = W4;
  bf16* Wvv = W4 + (size_t)1024 * Cd;
  bf16* Wqq = W4 + (size_t)2048 * Cd;
  bf16* Wm1 = W4 + (size_t)3072 * Cd;

  // zero the pad rows of W4 (3200..3327)
  zerobf_kernel<<<dim3(512), blk, 0, stream>>>(W4 + (size_t)3200 * Cd, 128 * Cd);

  // weight folds
  const bool use_ks = chunk_bytes >= (size_t)4 * 1152 * 1024 * sizeof(float);
  if (use_ks) {
    float* P = (float*)Xc;  // aliases dead chunk scratch
    transpose_kernel<<<dim3(16, 16), blk, 0, stream>>>(Wq, T, 1024, 1024);
    kgemm<<<dim3(9, 8, 4), blk, 0, stream>>>(WqStk, T, P, 1152, 1024, 1024, 1024);
    foldfin_kernel<<<dim3(4608), blk, 0, stream>>>(P, Wqq, 1152 * 1024);
    transpose_kernel<<<dim3(16, 16), blk, 0, stream>>>(Wk, T, 1024, 1024);
    kgemm<<<dim3(8, 8, 4), blk, 0, stream>>>(mhaWk, T, P, 1024, 1024, 1024, 1024);
    foldfin_kernel<<<dim3(4096), blk, 0, stream>>>(P, Wkk, 1024 * 1024);
    transpose_kernel<<<dim3(16, 16), blk, 0, stream>>>(Wv, T, 1024, 1024);
    kgemm<<<dim3(8, 8, 4), blk, 0, stream>>>(mhaWv, T, P, 1024, 1024, 1024, 1024);
    foldfin_kernel<<<dim3(4096), blk, 0, stream>>>(P, Wvv, 1024 * 1024);
    transpose_kernel<<<dim3(2, 16), blk, 0, stream>>>(mem_oW, T, 1024, 128);
    kgemm<<<dim3(16, 1, 4), blk, 0, stream>>>(W4, T, P, 2048, 128, 1024, 1024);
    foldfin_kernel<<<dim3(1024), blk, 0, stream>>>(P, Wc, 2048 * 128);
  } else {
    transpose_kernel<<<dim3(16, 16), blk, 0, stream>>>(Wq, T, 1024, 1024);
    mgemm<bf16, ACT_NONE, false><<<g128(1024, 1024), blk, 0, stream>>>(
        mhaWq, T, nullptr, Wqq, 1024, 1024, 1024, 1024, 1024, nullptr, nullptr, 0, nullptr, 0);
    mgemm<bf16, ACT_NONE, false><<<g128(128, 1024), blk, 0, stream>>>(
        mem_W1, T, nullptr, Wm1, 128, 1024, 1024, 1024, 1024, nullptr, nullptr, 0, nullptr, 0);
    transpose_kernel<<<dim3(16, 16), blk, 0, stream>>>(Wk, T, 1024, 1024);
    mgemm<bf16, ACT_NONE, false><<<g128(1024, 1024), blk, 0, stream>>>(
        mhaWk, T, nullptr, Wkk, 1024, 1024, 1024, 1024, 1024, nullptr, nullptr, 0, nullptr, 0);
    transpose_kernel<<<dim3(16, 16), blk, 0, stream>>>(Wv, T, 1024, 1024);
    mgemm<bf16, ACT_NONE, false><<<g128(1024, 1024), blk, 0, stream>>>(
        mhaWv, T, nullptr, Wvv, 1024, 1024, 1024, 1024, 1024, nullptr, nullptr, 0, nullptr, 0);
    transpose_kernel<<<dim3(2, 16), blk, 0, stream>>>(mem_oW, T, 1024, 128);
    mgemm<bf16, ACT_NONE, false><<<g128(2048, 128), blk, 0, stream>>>(
        W4, T, nullptr, Wc, 2048, 128, 1024, 1024, 128, nullptr, nullptr, 0, nullptr, 0);
  }
  pack_bias4<<<13, blk, 0, stream>>>(mhabk, mhabv, mhabq, mem_b1, bias4);
  kpvp_kernel<<<dim3(512), blk, 0, stream>>>(pm, mem_ob, W4, bias4, kp, vp, bkv);

  for (int r0 = 0; r0 < R; r0 += CR) {
    const int cr = (R - r0 < CR) ? (R - r0) : CR;
    const int n = cr * Cd;
    const bool big = (cr % 256) == 0;
    conv_kernel<<<dim3((n / 8 + 255) / 256), blk, 0, stream>>>(
        d_in[0], Xc, n, (size_t)r0 * Cd, flag);

    // packed x-projection: [k_x | v_x | q | h1=silu(...) | pad]
    if (big)
      qgemm<bf16, ACT_PSILU, true><<<g256(cr, NP4), dim3(512), 0, stream>>>(
          Xc, W4, bias4, QS4, cr, NP4, 1024, 1024, NP4, nullptr, nullptr, 0, nullptr, 3072);
    else
      mgemm<bf16, ACT_PSILU, true><<<g128(cr, NP4), blk, 0, stream>>>(
          Xc, W4, bias4, QS4, cr, NP4, 1024, 1024, NP4, nullptr, nullptr, 0, nullptr, 3072);

    // memory net tail: ln1 -> W2 -> ln2(+mstate) -> folded KVr (K=128)
    ln_kernel<bf16, bf16, false, 128, 128><<<cr, 128, 0, stream>>>(
        QS4 + 3072, ln1g, ln1b, nullptr, h2b, NP4);
    mgemm<bf16, ACT_NONE, true><<<g128(cr, 128), blk, 0, stream>>>(
        h2b, mem_W2, mem_b2, h1b, cr, 128, 128, 128, 128, nullptr, nullptr, 0, nullptr, 0);
    ln_kernel<bf16, bf16, true, 128, 128><<<cr, 128, 0, stream>>>(h1b, ln2g, ln2b, mstate, h2b, 128);
    mgemm<bf16, ACT_NONE, true><<<g128(cr, 2048), blk, 0, stream>>>(
        h2b, Wc, bkv, KVr, cr, 2048, 128, 128, 2048, nullptr, nullptr, 0, nullptr, 0);

    attn_kernel<<<dim3((cr / 64) * 8), dim3(512), 0, stream>>>(
        QS4 + 2048, NP4, KVr, 2048, QS4, NP4, kp, vp, Xc);

    // ao, gate-norm, fused gate*ao+x, final projection
    if (big)
      qgemm<bf16, ACT_NONE, true><<<g256(cr, Cd), dim3(512), 0, stream>>>(
          Xc, mhaWo, mhabo, Bb, cr, Cd, Cd, Cd, Cd, nullptr, nullptr, 0, nullptr, 0);
    else
      mgemm<bf16, ACT_NONE, true><<<g128(cr, Cd), blk, 0, stream>>>(
          Xc, mhaWo, mhabo, Bb, cr, Cd, Cd, Cd, Cd, nullptr, nullptr, 0, nullptr, 0);
    ln_kernel<bf16, bf16, false, 1024, 256><<<cr, 256, 0, stream>>>(Bb, gn_g, gn_b, nullptr, Cc, Cd);
    if (big) {
      qgemm<bf16, ACT_GATE, true><<<g256(cr, Cd), dim3(512), 0, stream>>>(
          Cc, gateW, gateb, Xc, cr, Cd, Cd, Cd, Cd, Bb, d_in[0], (size_t)r0 * Cd, flag, 0);
      qgemm<float, ACT_NONE, true><<<g256(cr, Cd), dim3(512), 0, stream>>>(
          Xc, outW, outb, (float*)d_out + (size_t)r0 * Cd, cr, Cd, Cd, Cd, Cd,
          nullptr, nullptr, 0, nullptr, 0);
    } else {
      mgemm<bf16, ACT_GATE, true><<<g128(cr, Cd), blk, 0, stream>>>(
          Cc, gateW, gateb, Xc, cr, Cd, Cd, Cd, Cd, Bb, d_in[0], (size_t)r0 * Cd, flag, 0);
      mgemm<float, ACT_NONE, true><<<g128(cr, Cd), blk, 0, stream>>>(
          Xc, outW, outb, (float*)d_out + (size_t)r0 * Cd, cr, Cd, Cd, Cd, Cd,
          nullptr, nullptr, 0, nullptr, 0);
    }
  }
}